// Round 1
// baseline (419.628 us; speedup 1.0000x reference)
//
#include <hip/hip_runtime.h>
#include <hip/hip_bf16.h>
#include <cmath>
#include <cstdint>

typedef __hip_bfloat16 bf16;
typedef __attribute__((ext_vector_type(4))) float f32x4;
typedef __attribute__((ext_vector_type(8))) short s16x8;

#define NB 2
#define NS 2048
#define ND 1024
#define NH 16
#define NHD 64

static __device__ __forceinline__ bf16 f2bf(float v){ return __float2bfloat16(v); }
static __device__ __forceinline__ unsigned short f2bfu(float v){
  bf16 b = __float2bfloat16(v);
  return *reinterpret_cast<unsigned short*>(&b);
}
static __device__ __forceinline__ float bfu2f(unsigned short u){
  union { unsigned int i; float f; } c; c.i = ((unsigned int)u) << 16; return c.f;
}

static __device__ __forceinline__ void gload_lds16(const void* g, void* l){
  __builtin_amdgcn_global_load_lds((const __attribute__((address_space(1))) void*)g,
                                   (__attribute__((address_space(3))) void*)l, 16, 0, 0);
}

// ---------------- prep kernels ----------------

__global__ __launch_bounds__(256) void convert_kernel(const float* __restrict__ src,
                                                       unsigned short* __restrict__ dst, int n4){
  int i = blockIdx.x * 256 + threadIdx.x;
  if (i >= n4) return;
  float4 v = ((const float4*)src)[i];
  ushort4 o;
  o.x = f2bfu(v.x); o.y = f2bfu(v.y); o.z = f2bfu(v.z); o.w = f2bfu(v.w);
  ((ushort4*)dst)[i] = o;
}

// src fp32 [R][C] -> dst bf16 [C][R]
__global__ __launch_bounds__(256) void transpose_convert(const float* __restrict__ src,
                                                          bf16* __restrict__ dst, int R, int C){
  __shared__ float tile[32][33];
  int c0 = blockIdx.x * 32, r0 = blockIdx.y * 32;
  int tx = threadIdx.x & 31, ty = threadIdx.x >> 5;
  #pragma unroll
  for (int i = ty; i < 32; i += 8)
    tile[i][tx] = src[(size_t)(r0 + i) * C + c0 + tx];
  __syncthreads();
  #pragma unroll
  for (int i = ty; i < 32; i += 8)
    dst[(size_t)(c0 + i) * R + r0 + tx] = f2bf(tile[tx][i]);
}

__global__ void pack_bias_kernel(const float* __restrict__ bq, const float* __restrict__ bk,
                                 const float* __restrict__ bv, float* __restrict__ dst){
  int i = blockIdx.x * 256 + threadIdx.x;
  if (i < 1024) dst[i] = bq[i];
  else if (i < 2048) dst[i] = bk[i - 1024];
  else if (i < 3072) dst[i] = bv[i - 2048];
}

// ---------------- GEMM (m97 structure) ----------------
// C[M][N](bf16) = A[M][K](bf16) @ BT[N][K](bf16)^T + bias, EPI: 0=bias, 1=QKV(v->vT), 2=bias+GELU
template<int EPI>
__global__ __launch_bounds__(256)
void gemm_bf16(const bf16* __restrict__ A, const bf16* __restrict__ BT,
               const float* __restrict__ bias, bf16* __restrict__ C,
               bf16* __restrict__ vT, int M, int N, int K)
{
  __shared__ bf16 As[2][128 * 32];
  __shared__ bf16 Bs[2][128 * 32];

  const int tid = threadIdx.x;
  const int lane = tid & 63;
  const int wave = tid >> 6;
  const int lr = lane & 15, lg = lane >> 4;
  const int wm = wave >> 1, wn = wave & 1;

  const int nbx = N >> 7;
  const int nwg = gridDim.x;
  const int wg = blockIdx.x;
  const int swz = (wg & 7) * (nwg >> 3) + (wg >> 3);   // nwg % 8 == 0 for all our shapes
  const int bx = swz % nbx, by = swz / nbx;
  const int m0 = by << 7, n0 = bx << 7;

  f32x4 acc[4][4] = {};

  const int NT = K >> 5;

  auto stage = [&](int t, int buf){
    const int k0 = t << 5;
    #pragma unroll
    for (int rch = 0; rch < 2; ++rch){
      int e = (rch * 256 + tid) * 8;
      int row = e >> 5, col = e & 31;
      gload_lds16(A + (size_t)(m0 + row) * K + k0 + col, &As[buf][e]);
    }
    #pragma unroll
    for (int rch = 0; rch < 2; ++rch){
      int e = (rch * 256 + tid) * 8;
      int row = e >> 5, col = e & 31;
      gload_lds16(BT + (size_t)(n0 + row) * K + k0 + col, &Bs[buf][e]);
    }
  };

  stage(0, 0);
  __syncthreads();

  for (int t = 0; t < NT; ++t){
    const int cur = t & 1;
    if (t + 1 < NT) stage(t + 1, cur ^ 1);
    s16x8 af[4], bfr[4];
    #pragma unroll
    for (int m = 0; m < 4; ++m)
      af[m] = *(const s16x8*)&As[cur][(wm * 64 + m * 16 + lr) * 32 + lg * 8];
    #pragma unroll
    for (int n = 0; n < 4; ++n)
      bfr[n] = *(const s16x8*)&Bs[cur][(wn * 64 + n * 16 + lr) * 32 + lg * 8];
    #pragma unroll
    for (int m = 0; m < 4; ++m)
      #pragma unroll
      for (int n = 0; n < 4; ++n)
        acc[m][n] = __builtin_amdgcn_mfma_f32_16x16x32_bf16(af[m], bfr[n], acc[m][n], 0, 0, 0);
    __syncthreads();
  }

  #pragma unroll
  for (int n = 0; n < 4; ++n){
    const int col = n0 + wn * 64 + n * 16 + lr;
    const float bv = bias[col];
    #pragma unroll
    for (int m = 0; m < 4; ++m){
      #pragma unroll
      for (int r = 0; r < 4; ++r){
        const int row = m0 + wm * 64 + m * 16 + lg * 4 + r;
        float v = acc[m][n][r] + bv;
        if (EPI == 2) v = 0.5f * v * (1.f + erff(v * 0.70710678118f));
        if (EPI == 1 && col >= 2048){
          int c2 = col - 2048;
          int h = c2 >> 6, d = c2 & 63;
          int b = row >> 11, s = row & 2047;
          vT[(((size_t)(b * NH + h)) * NHD + d) * NS + s] = f2bf(v);
        } else {
          C[(size_t)row * N + col] = f2bf(v);
        }
      }
    }
  }
}

// ---------------- flash attention ----------------
// qkv: [4096][3072] bf16 (q cols 0..1023, k cols 1024..2047), vT: [B*H][64][2048] bf16
// out: [4096][1024] bf16
__global__ __launch_bounds__(256)
void attn_kernel(const bf16* __restrict__ qkv, const bf16* __restrict__ vT,
                 bf16* __restrict__ out)
{
  const int qt = blockIdx.x;
  const int bh = blockIdx.y;
  const int b = bh >> 4, h = bh & 15;
  const int tid = threadIdx.x, lane = tid & 63, wave = tid >> 6;
  const int lr = lane & 15, lg = lane >> 4;
  const int q0 = qt * 64 + wave * 16;

  __shared__ bf16 VT_lds[64 * 64];        // XOR-swizzled (byte ^= (d&7)<<4)
  __shared__ bf16 P_lds[4][16 * 72];      // per-wave, padded stride 72

  const bf16* qrow = qkv + (size_t)(b * NS + q0 + lr) * 3072 + h * 64;
  const s16x8 qf0 = *(const s16x8*)(qrow + lg * 8);
  const s16x8 qf1 = *(const s16x8*)(qrow + 32 + lg * 8);

  const bf16* kbase = qkv + (size_t)b * NS * 3072 + 1024 + h * 64;
  const bf16* vtb = vT + (size_t)bh * NHD * NS;

  f32x4 oacc[4] = {};
  float mrow[4], lrowv[4];
  #pragma unroll
  for (int r = 0; r < 4; ++r){ mrow[r] = -3.0e38f; lrowv[r] = 0.f; }

  const int NT = qt + 1;
  for (int t = 0; t < NT; ++t){
    __syncthreads();   // all waves done reading VT_lds of previous tile
    // stage V^T tile with pre-swizzled global source (linear LDS dest)
    #pragma unroll
    for (int rch = 0; rch < 2; ++rch){
      int L = (rch * 256 + tid) * 16;          // dest byte in VT_lds
      int d = L >> 7;
      int cb = (L & 127) ^ ((d & 7) << 4);     // source col-byte (involution)
      int key = cb >> 1;
      gload_lds16(vtb + (size_t)d * NS + t * 64 + key, (char*)VT_lds + L);
    }
    // K fragments straight from global (L2-resident) + QK^T
    f32x4 sacc[4] = {};
    #pragma unroll
    for (int f = 0; f < 4; ++f){
      const bf16* krow = kbase + (size_t)(t * 64 + f * 16 + lr) * 3072;
      s16x8 kf0 = *(const s16x8*)(krow + lg * 8);
      s16x8 kf1 = *(const s16x8*)(krow + 32 + lg * 8);
      sacc[f] = __builtin_amdgcn_mfma_f32_16x16x32_bf16(qf0, kf0, sacc[f], 0, 0, 0);
      sacc[f] = __builtin_amdgcn_mfma_f32_16x16x32_bf16(qf1, kf1, sacc[f], 0, 0, 0);
    }
    const bool diag = (t == qt);
    #pragma unroll
    for (int f = 0; f < 4; ++f)
      #pragma unroll
      for (int r = 0; r < 4; ++r){
        float s = sacc[f][r] * 0.125f;
        if (diag){
          int key = t * 64 + f * 16 + lr;
          int qq = q0 + lg * 4 + r;
          if (key > qq) s = -1e30f;
        }
        sacc[f][r] = s;
      }
    // online softmax (rows spread over 16 lanes sharing lg)
    #pragma unroll
    for (int r = 0; r < 4; ++r){
      float mx = fmaxf(fmaxf(sacc[0][r], sacc[1][r]), fmaxf(sacc[2][r], sacc[3][r]));
      #pragma unroll
      for (int off = 1; off < 16; off <<= 1) mx = fmaxf(mx, __shfl_xor(mx, off));
      float mnew = fmaxf(mrow[r], mx);
      float alpha = __expf(mrow[r] - mnew);
      float sum = 0.f;
      #pragma unroll
      for (int f = 0; f < 4; ++f){
        float p = __expf(sacc[f][r] - mnew);
        sacc[f][r] = p;
        sum += p;
      }
      #pragma unroll
      for (int off = 1; off < 16; off <<= 1) sum += __shfl_xor(sum, off);
      lrowv[r] = lrowv[r] * alpha + sum;
      mrow[r] = mnew;
      #pragma unroll
      for (int f = 0; f < 4; ++f) oacc[f][r] *= alpha;
    }
    // P -> LDS (per wave region)
    #pragma unroll
    for (int f = 0; f < 4; ++f)
      #pragma unroll
      for (int r = 0; r < 4; ++r)
        P_lds[wave][(lg * 4 + r) * 72 + f * 16 + lr] = f2bf(sacc[f][r]);
    __syncthreads();   // VT staging (vmcnt) + P writes drained
    // P @ V
    #pragma unroll
    for (int ks = 0; ks < 2; ++ks){
      s16x8 pf = *(const s16x8*)&P_lds[wave][lr * 72 + ks * 32 + lg * 8];
      #pragma unroll
      for (int f = 0; f < 4; ++f){
        int dd = f * 16 + lr;
        int lin = dd * 128 + (ks * 32 + lg * 8) * 2;
        int addr = lin ^ ((dd & 7) << 4);
        s16x8 vf = *(const s16x8*)((const char*)VT_lds + addr);
        oacc[f] = __builtin_amdgcn_mfma_f32_16x16x32_bf16(pf, vf, oacc[f], 0, 0, 0);
      }
    }
  }
  #pragma unroll
  for (int f = 0; f < 4; ++f)
    #pragma unroll
    for (int r = 0; r < 4; ++r){
      float v = oacc[f][r] / lrowv[r];
      out[(size_t)(b * NS + q0 + lg * 4 + r) * ND + h * 64 + f * 16 + lr] = f2bf(v);
    }
}

// ---------------- residual + LayerNorm ----------------
__global__ __launch_bounds__(256)
void ln_kernel(const bf16* __restrict__ a, const bf16* __restrict__ dn,
               const float* __restrict__ gamma, const float* __restrict__ beta,
               float* __restrict__ out)
{
  const int row = blockIdx.x;
  const int tid = threadIdx.x;
  const int lane = tid & 63, wave = tid >> 6;
  const size_t base = (size_t)row * ND;
  ushort4 ua = *(const ushort4*)((const unsigned short*)a + base + tid * 4);
  ushort4 ud = *(const ushort4*)((const unsigned short*)dn + base + tid * 4);
  float y[4];
  y[0] = bfu2f(ua.x) + bfu2f(ud.x);
  y[1] = bfu2f(ua.y) + bfu2f(ud.y);
  y[2] = bfu2f(ua.z) + bfu2f(ud.z);
  y[3] = bfu2f(ua.w) + bfu2f(ud.w);
  float s = y[0] + y[1] + y[2] + y[3];
  float ss = y[0]*y[0] + y[1]*y[1] + y[2]*y[2] + y[3]*y[3];
  #pragma unroll
  for (int off = 1; off < 64; off <<= 1){
    s  += __shfl_xor(s, off);
    ss += __shfl_xor(ss, off);
  }
  __shared__ float rs[4], rss[4];
  if (lane == 0){ rs[wave] = s; rss[wave] = ss; }
  __syncthreads();
  const float S  = rs[0] + rs[1] + rs[2] + rs[3];
  const float SS = rss[0] + rss[1] + rss[2] + rss[3];
  const float mu = S * (1.f / 1024.f);
  const float var = SS * (1.f / 1024.f) - mu * mu;
  const float inv = rsqrtf(var + 1e-6f);
  #pragma unroll
  for (int j = 0; j < 4; ++j){
    int c = tid * 4 + j;
    out[base + c] = (y[j] - mu) * inv * gamma[c] + beta[c];
  }
}

// ---------------- launcher ----------------
extern "C" void kernel_launch(void* const* d_in, const int* in_sizes, int n_in,
                              void* d_out, int out_size, void* d_ws, size_t ws_size,
                              hipStream_t stream)
{
  (void)in_sizes; (void)n_in; (void)out_size; (void)ws_size;
  const float* x  = (const float*)d_in[0];
  const float* Wq = (const float*)d_in[2];
  const float* bq = (const float*)d_in[3];
  const float* Wk = (const float*)d_in[4];
  const float* bk = (const float*)d_in[5];
  const float* Wv = (const float*)d_in[6];
  const float* bv = (const float*)d_in[7];
  const float* Wo = (const float*)d_in[8];
  const float* bo = (const float*)d_in[9];
  const float* W1 = (const float*)d_in[10];
  const float* b1 = (const float*)d_in[11];
  const float* W2 = (const float*)d_in[12];
  const float* b2 = (const float*)d_in[13];
  const float* gamma = (const float*)d_in[14];
  const float* beta  = (const float*)d_in[15];
  float* out = (float*)d_out;

  char* ws = (char*)d_ws;
  bf16* x_bf    = (bf16*)(ws + 0);          //  8,388,608
  bf16* wqkvT   = (bf16*)(ws + 8388608);    //  6,291,456  [3072][1024]
  bf16* woT     = (bf16*)(ws + 14680064);   //  2,097,152
  bf16* w1T     = (bf16*)(ws + 16777216);   //  8,388,608  [4096][1024]
  bf16* w2T     = (bf16*)(ws + 25165824);   //  8,388,608  [1024][4096]
  float* bqkv   = (float*)(ws + 33554432);  //     12,288
  bf16* qkv     = (bf16*)(ws + 33566720);   // 25,165,824  [4096][3072]
  bf16* vT      = (bf16*)(ws + 58732544);   //  8,388,608  [32][64][2048]
  bf16* attn    = (bf16*)(ws + 67121152);   //  8,388,608
  bf16* attnout = (bf16*)(ws + 75509760);   //  8,388,608
  bf16* down    = (bf16*)(ws + 83898368);   //  8,388,608
  bf16* hbuf    = (bf16*)(ws + 92286976);   // 33,554,432  [4096][4096]

  convert_kernel<<<4096, 256, 0, stream>>>(x, (unsigned short*)x_bf, 1048576);
  transpose_convert<<<dim3(32, 32), 256, 0, stream>>>(Wq, wqkvT,               1024, 1024);
  transpose_convert<<<dim3(32, 32), 256, 0, stream>>>(Wk, wqkvT + 1024 * 1024, 1024, 1024);
  transpose_convert<<<dim3(32, 32), 256, 0, stream>>>(Wv, wqkvT + 2048 * 1024, 1024, 1024);
  transpose_convert<<<dim3(32, 32), 256, 0, stream>>>(Wo, woT, 1024, 1024);
  transpose_convert<<<dim3(128, 32), 256, 0, stream>>>(W1, w1T, 1024, 4096);
  transpose_convert<<<dim3(32, 128), 256, 0, stream>>>(W2, w2T, 4096, 1024);
  pack_bias_kernel<<<12, 256, 0, stream>>>(bq, bk, bv, bqkv);

  gemm_bf16<1><<<768, 256, 0, stream>>>(x_bf, wqkvT, bqkv, qkv, vT, 4096, 3072, 1024);
  attn_kernel<<<dim3(32, 32), 256, 0, stream>>>(qkv, vT, attn);
  gemm_bf16<0><<<256, 256, 0, stream>>>(attn, woT, bo, attnout, nullptr, 4096, 1024, 1024);
  gemm_bf16<2><<<1024, 256, 0, stream>>>(attnout, w1T, b1, hbuf, nullptr, 4096, 4096, 1024);
  gemm_bf16<0><<<256, 256, 0, stream>>>(hbuf, w2T, b2, down, nullptr, 4096, 1024, 4096);
  ln_kernel<<<4096, 256, 0, stream>>>(attnout, down, gamma, beta, out);
}

// Round 2
// 364.582 us; speedup vs baseline: 1.1510x; 1.1510x over previous
//
#include <hip/hip_runtime.h>
#include <hip/hip_bf16.h>
#include <cmath>
#include <cstdint>

typedef __hip_bfloat16 bf16;
typedef __attribute__((ext_vector_type(4))) float f32x4;
typedef __attribute__((ext_vector_type(8))) short s16x8;

#define NB 2
#define NS 2048
#define ND 1024
#define NH 16
#define NHD 64

static __device__ __forceinline__ bf16 f2bf(float v){ return __float2bfloat16(v); }
static __device__ __forceinline__ unsigned short f2bfu(float v){
  bf16 b = __float2bfloat16(v);
  return *reinterpret_cast<unsigned short*>(&b);
}
static __device__ __forceinline__ float bfu2f(unsigned short u){
  union { unsigned int i; float f; } c; c.i = ((unsigned int)u) << 16; return c.f;
}

static __device__ __forceinline__ void gload_lds16(const void* g, void* l){
  __builtin_amdgcn_global_load_lds((const __attribute__((address_space(1))) void*)g,
                                   (__attribute__((address_space(3))) void*)l, 16, 0, 0);
}

// ---------------- prep kernels ----------------

__global__ __launch_bounds__(256) void convert_kernel(const float* __restrict__ src,
                                                       unsigned short* __restrict__ dst, int n4){
  int i = blockIdx.x * 256 + threadIdx.x;
  if (i >= n4) return;
  float4 v = ((const float4*)src)[i];
  ushort4 o;
  o.x = f2bfu(v.x); o.y = f2bfu(v.y); o.z = f2bfu(v.z); o.w = f2bfu(v.w);
  ((ushort4*)dst)[i] = o;
}

// src fp32 [R][C] -> dst bf16 [C][R]
__global__ __launch_bounds__(256) void transpose_convert(const float* __restrict__ src,
                                                          bf16* __restrict__ dst, int R, int C){
  __shared__ float tile[32][33];
  int c0 = blockIdx.x * 32, r0 = blockIdx.y * 32;
  int tx = threadIdx.x & 31, ty = threadIdx.x >> 5;
  #pragma unroll
  for (int i = ty; i < 32; i += 8)
    tile[i][tx] = src[(size_t)(r0 + i) * C + c0 + tx];
  __syncthreads();
  #pragma unroll
  for (int i = ty; i < 32; i += 8)
    dst[(size_t)(c0 + i) * R + r0 + tx] = f2bf(tile[tx][i]);
}

__global__ void pack_bias_kernel(const float* __restrict__ bq, const float* __restrict__ bk,
                                 const float* __restrict__ bv, float* __restrict__ dst){
  int i = blockIdx.x * 256 + threadIdx.x;
  if (i < 1024) dst[i] = bq[i];
  else if (i < 2048) dst[i] = bk[i - 1024];
  else if (i < 3072) dst[i] = bv[i - 2048];
}

// ---------------- GEMM (m97 structure) ----------------
// C[M][N](bf16) = A[M][K](bf16) @ BT[N][K](bf16)^T + bias, EPI: 0=bias, 1=QKV(v->vT), 2=bias+GELU
template<int EPI>
__global__ __launch_bounds__(256)
void gemm_bf16(const bf16* __restrict__ A, const bf16* __restrict__ BT,
               const float* __restrict__ bias, bf16* __restrict__ C,
               bf16* __restrict__ vT, int M, int N, int K)
{
  __shared__ bf16 As[2][128 * 32];
  __shared__ bf16 Bs[2][128 * 32];

  const int tid = threadIdx.x;
  const int lane = tid & 63;
  const int wave = tid >> 6;
  const int lr = lane & 15, lg = lane >> 4;
  const int wm = wave >> 1, wn = wave & 1;

  const int nbx = N >> 7;
  const int nwg = gridDim.x;
  const int wg = blockIdx.x;
  const int swz = (wg & 7) * (nwg >> 3) + (wg >> 3);   // nwg % 8 == 0 for all our shapes
  const int bx = swz % nbx, by = swz / nbx;
  const int m0 = by << 7, n0 = bx << 7;

  f32x4 acc[4][4] = {};

  const int NT = K >> 5;

  auto stage = [&](int t, int buf){
    const int k0 = t << 5;
    #pragma unroll
    for (int rch = 0; rch < 2; ++rch){
      int e = (rch * 256 + tid) * 8;
      int row = e >> 5, col = e & 31;
      gload_lds16(A + (size_t)(m0 + row) * K + k0 + col, &As[buf][e]);
    }
    #pragma unroll
    for (int rch = 0; rch < 2; ++rch){
      int e = (rch * 256 + tid) * 8;
      int row = e >> 5, col = e & 31;
      gload_lds16(BT + (size_t)(n0 + row) * K + k0 + col, &Bs[buf][e]);
    }
  };

  stage(0, 0);
  __syncthreads();

  for (int t = 0; t < NT; ++t){
    const int cur = t & 1;
    if (t + 1 < NT) stage(t + 1, cur ^ 1);
    s16x8 af[4], bfr[4];
    #pragma unroll
    for (int m = 0; m < 4; ++m)
      af[m] = *(const s16x8*)&As[cur][(wm * 64 + m * 16 + lr) * 32 + lg * 8];
    #pragma unroll
    for (int n = 0; n < 4; ++n)
      bfr[n] = *(const s16x8*)&Bs[cur][(wn * 64 + n * 16 + lr) * 32 + lg * 8];
    #pragma unroll
    for (int m = 0; m < 4; ++m)
      #pragma unroll
      for (int n = 0; n < 4; ++n)
        acc[m][n] = __builtin_amdgcn_mfma_f32_16x16x32_bf16(af[m], bfr[n], acc[m][n], 0, 0, 0);
    __syncthreads();
  }

  #pragma unroll
  for (int n = 0; n < 4; ++n){
    const int col = n0 + wn * 64 + n * 16 + lr;
    const float bv = bias[col];
    #pragma unroll
    for (int m = 0; m < 4; ++m){
      #pragma unroll
      for (int r = 0; r < 4; ++r){
        const int row = m0 + wm * 64 + m * 16 + lg * 4 + r;
        float v = acc[m][n][r] + bv;
        if (EPI == 2) v = 0.5f * v * (1.f + erff(v * 0.70710678118f));
        if (EPI == 1 && col >= 2048){
          int c2 = col - 2048;
          int h = c2 >> 6, d = c2 & 63;
          int b = row >> 11, s = row & 2047;
          vT[(((size_t)(b * NH + h)) * NHD + d) * NS + s] = f2bf(v);
        } else {
          C[(size_t)row * N + col] = f2bf(v);
        }
      }
    }
  }
}

// ---------------- flash attention (barrier-free, pair-balanced waves) ----------------
// qkv: [4096][3072] bf16 (q cols 0..1023, k cols 1024..2047), vT: [B*H][64][2048] bf16
// out: [4096][1024] bf16
// Each wave owns two 16-row q-strips (p, 127-p) -> exactly 33-34 KV tiles per wave.
// K/V fragments read directly from global (L2-resident). No __syncthreads in main loop.
__global__ __launch_bounds__(256, 2)
void attn_kernel(const bf16* __restrict__ qkv, const bf16* __restrict__ vT,
                 bf16* __restrict__ out)
{
  const int bh = blockIdx.y;
  const int b = bh >> 4, h = bh & 15;
  const int tid = threadIdx.x, lane = tid & 63, wave = tid >> 6;
  const int lr = lane & 15, lg = lane >> 4;
  const int p = blockIdx.x * 4 + wave;          // 0..63

  __shared__ bf16 P_lds[4][16 * 72];            // per-wave region, pad stride 72

  const bf16* kbase = qkv + (size_t)b * NS * 3072 + 1024 + h * 64;
  const bf16* vtb = vT + (size_t)bh * NHD * NS;

  #pragma unroll 1
  for (int half = 0; half < 2; ++half){
    const int s = half ? p : (127 - p);         // long strip first
    const int q0 = s * 16;
    const int nt = (s >> 2) + 1;

    const bf16* qrow = qkv + (size_t)(b * NS + q0 + lr) * 3072 + h * 64;
    const s16x8 qf0 = *(const s16x8*)(qrow + lg * 8);
    const s16x8 qf1 = *(const s16x8*)(qrow + 32 + lg * 8);

    f32x4 oacc[4] = {};
    float mrow[4], lsum[4];
    #pragma unroll
    for (int r = 0; r < 4; ++r){ mrow[r] = -3.0e38f; lsum[r] = 0.f; }

    // preload K fragments for tile 0
    s16x8 kf[2][4];
    #pragma unroll
    for (int f = 0; f < 4; ++f){
      const bf16* kr = kbase + (size_t)(f * 16 + lr) * 3072;
      kf[0][f] = *(const s16x8*)(kr + lg * 8);
      kf[1][f] = *(const s16x8*)(kr + 32 + lg * 8);
    }

    #pragma unroll 1
    for (int t = 0; t < nt; ++t){
      // issue V fragment loads early (consumed after softmax)
      s16x8 vf[2][4];
      #pragma unroll
      for (int ks = 0; ks < 2; ++ks)
        #pragma unroll
        for (int f = 0; f < 4; ++f)
          vf[ks][f] = *(const s16x8*)(vtb + (size_t)(f * 16 + lr) * NS + t * 64 + ks * 32 + lg * 8);

      // QK^T
      f32x4 sacc[4] = {};
      #pragma unroll
      for (int f = 0; f < 4; ++f){
        sacc[f] = __builtin_amdgcn_mfma_f32_16x16x32_bf16(qf0, kf[0][f], sacc[f], 0, 0, 0);
        sacc[f] = __builtin_amdgcn_mfma_f32_16x16x32_bf16(qf1, kf[1][f], sacc[f], 0, 0, 0);
      }

      // prefetch next tile's K fragments
      s16x8 kn[2][4];
      if (t + 1 < nt){
        #pragma unroll
        for (int f = 0; f < 4; ++f){
          const bf16* kr = kbase + (size_t)((t + 1) * 64 + f * 16 + lr) * 3072;
          kn[0][f] = *(const s16x8*)(kr + lg * 8);
          kn[1][f] = *(const s16x8*)(kr + 32 + lg * 8);
        }
      }

      // scale + causal mask (only final tile of this strip can straddle diagonal)
      const bool diag = (t == nt - 1);
      #pragma unroll
      for (int f = 0; f < 4; ++f)
        #pragma unroll
        for (int r = 0; r < 4; ++r){
          float sv = sacc[f][r] * 0.125f;
          if (diag){
            int key = t * 64 + f * 16 + lr;
            int qq = q0 + lg * 4 + r;
            if (key > qq) sv = -1e30f;
          }
          sacc[f][r] = sv;
        }

      // online softmax (row spread over 16 lanes sharing lg)
      #pragma unroll
      for (int r = 0; r < 4; ++r){
        float mx = fmaxf(fmaxf(sacc[0][r], sacc[1][r]), fmaxf(sacc[2][r], sacc[3][r]));
        #pragma unroll
        for (int off = 1; off < 16; off <<= 1) mx = fmaxf(mx, __shfl_xor(mx, off));
        float mnew = fmaxf(mrow[r], mx);
        float alpha = __expf(mrow[r] - mnew);
        float sum = 0.f;
        #pragma unroll
        for (int f = 0; f < 4; ++f){
          float pv = __expf(sacc[f][r] - mnew);
          sacc[f][r] = pv;
          sum += pv;
        }
        #pragma unroll
        for (int off = 1; off < 16; off <<= 1) sum += __shfl_xor(sum, off);
        lsum[r] = lsum[r] * alpha + sum;
        mrow[r] = mnew;
        #pragma unroll
        for (int f = 0; f < 4; ++f) oacc[f][r] *= alpha;
      }

      // P -> per-wave LDS (wave-local; no barrier needed)
      #pragma unroll
      for (int f = 0; f < 4; ++f)
        #pragma unroll
        for (int r = 0; r < 4; ++r)
          P_lds[wave][(lg * 4 + r) * 72 + f * 16 + lr] = f2bf(sacc[f][r]);

      // P @ V
      #pragma unroll
      for (int ks = 0; ks < 2; ++ks){
        s16x8 pf = *(const s16x8*)&P_lds[wave][lr * 72 + ks * 32 + lg * 8];
        #pragma unroll
        for (int f = 0; f < 4; ++f)
          oacc[f] = __builtin_amdgcn_mfma_f32_16x16x32_bf16(pf, vf[ks][f], oacc[f], 0, 0, 0);
      }

      if (t + 1 < nt){
        #pragma unroll
        for (int ks = 0; ks < 2; ++ks)
          #pragma unroll
          for (int f = 0; f < 4; ++f)
            kf[ks][f] = kn[ks][f];
      }
    }

    #pragma unroll
    for (int f = 0; f < 4; ++f)
      #pragma unroll
      for (int r = 0; r < 4; ++r){
        float v = oacc[f][r] / lsum[r];
        out[(size_t)(b * NS + q0 + lg * 4 + r) * ND + h * 64 + f * 16 + lr] = f2bf(v);
      }
  }
}

// ---------------- residual + LayerNorm ----------------
__global__ __launch_bounds__(256)
void ln_kernel(const bf16* __restrict__ a, const bf16* __restrict__ dn,
               const float* __restrict__ gamma, const float* __restrict__ beta,
               float* __restrict__ out)
{
  const int row = blockIdx.x;
  const int tid = threadIdx.x;
  const int lane = tid & 63, wave = tid >> 6;
  const size_t base = (size_t)row * ND;
  ushort4 ua = *(const ushort4*)((const unsigned short*)a + base + tid * 4);
  ushort4 ud = *(const ushort4*)((const unsigned short*)dn + base + tid * 4);
  float y[4];
  y[0] = bfu2f(ua.x) + bfu2f(ud.x);
  y[1] = bfu2f(ua.y) + bfu2f(ud.y);
  y[2] = bfu2f(ua.z) + bfu2f(ud.z);
  y[3] = bfu2f(ua.w) + bfu2f(ud.w);
  float s = y[0] + y[1] + y[2] + y[3];
  float ss = y[0]*y[0] + y[1]*y[1] + y[2]*y[2] + y[3]*y[3];
  #pragma unroll
  for (int off = 1; off < 64; off <<= 1){
    s  += __shfl_xor(s, off);
    ss += __shfl_xor(ss, off);
  }
  __shared__ float rs[4], rss[4];
  if (lane == 0){ rs[wave] = s; rss[wave] = ss; }
  __syncthreads();
  const float S  = rs[0] + rs[1] + rs[2] + rs[3];
  const float SS = rss[0] + rss[1] + rss[2] + rss[3];
  const float mu = S * (1.f / 1024.f);
  const float var = SS * (1.f / 1024.f) - mu * mu;
  const float inv = rsqrtf(var + 1e-6f);
  #pragma unroll
  for (int j = 0; j < 4; ++j){
    int c = tid * 4 + j;
    out[base + c] = (y[j] - mu) * inv * gamma[c] + beta[c];
  }
}

// ---------------- launcher ----------------
extern "C" void kernel_launch(void* const* d_in, const int* in_sizes, int n_in,
                              void* d_out, int out_size, void* d_ws, size_t ws_size,
                              hipStream_t stream)
{
  (void)in_sizes; (void)n_in; (void)out_size; (void)ws_size;
  const float* x  = (const float*)d_in[0];
  const float* Wq = (const float*)d_in[2];
  const float* bq = (const float*)d_in[3];
  const float* Wk = (const float*)d_in[4];
  const float* bk = (const float*)d_in[5];
  const float* Wv = (const float*)d_in[6];
  const float* bv = (const float*)d_in[7];
  const float* Wo = (const float*)d_in[8];
  const float* bo = (const float*)d_in[9];
  const float* W1 = (const float*)d_in[10];
  const float* b1 = (const float*)d_in[11];
  const float* W2 = (const float*)d_in[12];
  const float* b2 = (const float*)d_in[13];
  const float* gamma = (const float*)d_in[14];
  const float* beta  = (const float*)d_in[15];
  float* out = (float*)d_out;

  char* ws = (char*)d_ws;
  bf16* x_bf    = (bf16*)(ws + 0);          //  8,388,608
  bf16* wqkvT   = (bf16*)(ws + 8388608);    //  6,291,456  [3072][1024]
  bf16* woT     = (bf16*)(ws + 14680064);   //  2,097,152
  bf16* w1T     = (bf16*)(ws + 16777216);   //  8,388,608  [4096][1024]
  bf16* w2T     = (bf16*)(ws + 25165824);   //  8,388,608  [1024][4096]
  float* bqkv   = (float*)(ws + 33554432);  //     12,288
  bf16* qkv     = (bf16*)(ws + 33566720);   // 25,165,824  [4096][3072]
  bf16* vT      = (bf16*)(ws + 58732544);   //  8,388,608  [32][64][2048]
  bf16* attn    = (bf16*)(ws + 67121152);   //  8,388,608
  bf16* attnout = (bf16*)(ws + 75509760);   //  8,388,608
  bf16* down    = (bf16*)(ws + 83898368);   //  8,388,608
  bf16* hbuf    = (bf16*)(ws + 92286976);   // 33,554,432  [4096][4096]

  convert_kernel<<<4096, 256, 0, stream>>>(x, (unsigned short*)x_bf, 1048576);
  transpose_convert<<<dim3(32, 32), 256, 0, stream>>>(Wq, wqkvT,               1024, 1024);
  transpose_convert<<<dim3(32, 32), 256, 0, stream>>>(Wk, wqkvT + 1024 * 1024, 1024, 1024);
  transpose_convert<<<dim3(32, 32), 256, 0, stream>>>(Wv, wqkvT + 2048 * 1024, 1024, 1024);
  transpose_convert<<<dim3(32, 32), 256, 0, stream>>>(Wo, woT, 1024, 1024);
  transpose_convert<<<dim3(128, 32), 256, 0, stream>>>(W1, w1T, 1024, 4096);
  transpose_convert<<<dim3(32, 128), 256, 0, stream>>>(W2, w2T, 4096, 1024);
  pack_bias_kernel<<<12, 256, 0, stream>>>(bq, bk, bv, bqkv);

  gemm_bf16<1><<<768, 256, 0, stream>>>(x_bf, wqkvT, bqkv, qkv, vT, 4096, 3072, 1024);
  attn_kernel<<<dim3(16, 32), 256, 0, stream>>>(qkv, vT, attn);
  gemm_bf16<0><<<256, 256, 0, stream>>>(attn, woT, bo, attnout, nullptr, 4096, 1024, 1024);
  gemm_bf16<2><<<1024, 256, 0, stream>>>(attnout, w1T, b1, hbuf, nullptr, 4096, 4096, 1024);
  gemm_bf16<0><<<256, 256, 0, stream>>>(hbuf, w2T, b2, down, nullptr, 4096, 1024, 4096);
  ln_kernel<<<4096, 256, 0, stream>>>(attnout, down, gamma, beta, out);
}

// Round 3
// 320.314 us; speedup vs baseline: 1.3101x; 1.1382x over previous
//
#include <hip/hip_runtime.h>
#include <hip/hip_bf16.h>
#include <cmath>
#include <cstdint>

typedef __hip_bfloat16 bf16;
typedef __attribute__((ext_vector_type(4))) float f32x4;
typedef __attribute__((ext_vector_type(8))) short s16x8;

#define NB 2
#define NS 2048
#define ND 1024
#define NH 16
#define NHD 64

static __device__ __forceinline__ bf16 f2bf(float v){ return __float2bfloat16(v); }
static __device__ __forceinline__ unsigned short f2bfu(float v){
  bf16 b = __float2bfloat16(v);
  return *reinterpret_cast<unsigned short*>(&b);
}
static __device__ __forceinline__ float bfu2f(unsigned short u){
  union { unsigned int i; float f; } c; c.i = ((unsigned int)u) << 16; return c.f;
}

static __device__ __forceinline__ void gload_lds16(const void* g, void* l){
  __builtin_amdgcn_global_load_lds((const __attribute__((address_space(1))) void*)g,
                                   (__attribute__((address_space(3))) void*)l, 16, 0, 0);
}

// ---------------- prep kernels ----------------

__global__ __launch_bounds__(256) void convert_kernel(const float* __restrict__ src,
                                                       unsigned short* __restrict__ dst, int n4){
  int i = blockIdx.x * 256 + threadIdx.x;
  if (i >= n4) return;
  float4 v = ((const float4*)src)[i];
  ushort4 o;
  o.x = f2bfu(v.x); o.y = f2bfu(v.y); o.z = f2bfu(v.z); o.w = f2bfu(v.w);
  ((ushort4*)dst)[i] = o;
}

// src fp32 [R][C] -> dst bf16 [C][R]
__global__ __launch_bounds__(256) void transpose_convert(const float* __restrict__ src,
                                                          bf16* __restrict__ dst, int R, int C){
  __shared__ float tile[32][33];
  int c0 = blockIdx.x * 32, r0 = blockIdx.y * 32;
  int tx = threadIdx.x & 31, ty = threadIdx.x >> 5;
  #pragma unroll
  for (int i = ty; i < 32; i += 8)
    tile[i][tx] = src[(size_t)(r0 + i) * C + c0 + tx];
  __syncthreads();
  #pragma unroll
  for (int i = ty; i < 32; i += 8)
    dst[(size_t)(c0 + i) * R + r0 + tx] = f2bf(tile[tx][i]);
}

__global__ void pack_bias_kernel(const float* __restrict__ bq, const float* __restrict__ bk,
                                 const float* __restrict__ bv, float* __restrict__ dst){
  int i = blockIdx.x * 256 + threadIdx.x;
  if (i < 1024) dst[i] = bq[i];
  else if (i < 2048) dst[i] = bk[i - 1024];
  else if (i < 3072) dst[i] = bv[i - 2048];
}

// ---------------- GEMM (m97 structure, tile BM x 128) ----------------
// C[M][N](bf16) = A[M][K](bf16) @ BT[N][K](bf16)^T + bias
// EPI: 0=bias, 1=QKV(v->vT), 2=bias+GELU.  BM in {64,128}.
template<int EPI, int BM>
__global__ __launch_bounds__(256)
void gemm_bf16(const bf16* __restrict__ A, const bf16* __restrict__ BT,
               const float* __restrict__ bias, bf16* __restrict__ C,
               bf16* __restrict__ vT, int M, int N, int K)
{
  constexpr int MF = BM / 32;        // M-frags per wave
  constexpr int RA = BM / 64;        // A staging rounds
  __shared__ bf16 As[2][BM * 32];
  __shared__ bf16 Bs[2][128 * 32];

  const int tid = threadIdx.x;
  const int lane = tid & 63;
  const int wave = tid >> 6;
  const int lr = lane & 15, lg = lane >> 4;
  const int wm = wave >> 1, wn = wave & 1;

  const int nbx = N >> 7;
  const int nwg = gridDim.x;
  const int wg = blockIdx.x;
  const int swz = (wg & 7) * (nwg >> 3) + (wg >> 3);   // nwg % 8 == 0 for all our shapes
  const int bx = swz % nbx, by = swz / nbx;
  const int m0 = by * BM, n0 = bx << 7;

  f32x4 acc[MF][4] = {};

  const int NT = K >> 5;

  auto stage = [&](int t, int buf){
    const int k0 = t << 5;
    #pragma unroll
    for (int rch = 0; rch < RA; ++rch){
      int e = (rch * 256 + tid) * 8;
      int row = e >> 5, col = e & 31;
      gload_lds16(A + (size_t)(m0 + row) * K + k0 + col, &As[buf][e]);
    }
    #pragma unroll
    for (int rch = 0; rch < 2; ++rch){
      int e = (rch * 256 + tid) * 8;
      int row = e >> 5, col = e & 31;
      gload_lds16(BT + (size_t)(n0 + row) * K + k0 + col, &Bs[buf][e]);
    }
  };

  stage(0, 0);
  __syncthreads();

  for (int t = 0; t < NT; ++t){
    const int cur = t & 1;
    if (t + 1 < NT) stage(t + 1, cur ^ 1);
    s16x8 af[MF], bfr[4];
    #pragma unroll
    for (int m = 0; m < MF; ++m)
      af[m] = *(const s16x8*)&As[cur][(wm * (BM / 2) + m * 16 + lr) * 32 + lg * 8];
    #pragma unroll
    for (int n = 0; n < 4; ++n)
      bfr[n] = *(const s16x8*)&Bs[cur][(wn * 64 + n * 16 + lr) * 32 + lg * 8];
    #pragma unroll
    for (int m = 0; m < MF; ++m)
      #pragma unroll
      for (int n = 0; n < 4; ++n)
        acc[m][n] = __builtin_amdgcn_mfma_f32_16x16x32_bf16(af[m], bfr[n], acc[m][n], 0, 0, 0);
    __syncthreads();
  }

  #pragma unroll
  for (int n = 0; n < 4; ++n){
    const int col = n0 + wn * 64 + n * 16 + lr;
    const float bv = bias[col];
    #pragma unroll
    for (int m = 0; m < MF; ++m){
      #pragma unroll
      for (int r = 0; r < 4; ++r){
        const int row = m0 + wm * (BM / 2) + m * 16 + lg * 4 + r;
        float v = acc[m][n][r] + bv;
        if (EPI == 2) v = 0.5f * v * (1.f + erff(v * 0.70710678118f));
        if (EPI == 1 && col >= 2048){
          int c2 = col - 2048;
          int h = c2 >> 6, d = c2 & 63;
          int b = row >> 11, s = row & 2047;
          vT[(((size_t)(b * NH + h)) * NHD + d) * NS + s] = f2bf(v);
        } else {
          C[(size_t)row * N + col] = f2bf(v);
        }
      }
    }
  }
}

// ---------------- flash attention (block-level KV sharing) ----------------
// qkv: [4096][3072] bf16 (q cols 0..1023, k cols 1024..2047), vT: [B*H][64][2048] bf16
// out: [4096][1024] bf16
// Block = one 64-row q-tile (4 waves x 16 rows). K/V tiles staged into
// fragment-ordered LDS (chunk c = ks*4+f, 1KB per chunk, dest = c*1KB + lane*16B),
// double-buffered, one barrier per KV tile.
__global__ __launch_bounds__(256, 3)
void attn_kernel(const bf16* __restrict__ qkv, const bf16* __restrict__ vT,
                 bf16* __restrict__ out)
{
  const int bh = blockIdx.y;
  const int b = bh >> 4, h = bh & 15;
  const int tid = threadIdx.x, lane = tid & 63, wave = tid >> 6;
  const int lr = lane & 15, lg = lane >> 4;
  const int qt = 31 - blockIdx.x;              // longest q-tiles dispatch first
  const int q0 = qt * 64 + wave * 16;
  const int nt = qt + 1;

  __shared__ bf16 K_lds[2][8 * 512];           // fragment-ordered, 8KB per buffer
  __shared__ bf16 V_lds[2][8 * 512];
  __shared__ bf16 P_lds[4][16 * 72];           // per-wave, pad stride 72

  const bf16* kbase = qkv + (size_t)b * NS * 3072 + 1024 + h * 64;
  const bf16* vtb = vT + (size_t)bh * NHD * NS;

  const bf16* qrow = qkv + (size_t)(b * NS + q0 + lr) * 3072 + h * 64;
  const s16x8 qf0 = *(const s16x8*)(qrow + lg * 8);
  const s16x8 qf1 = *(const s16x8*)(qrow + 32 + lg * 8);

  // wave w stages chunks {2w, 2w+1} of K and V; chunk c = ks*4+f holds the
  // 16B-per-lane fragment (row = f*16+lr, cols ks*32+lg*8..+7) at c*1KB+lane*16B.
  auto stage = [&](int t, int buf){
    #pragma unroll
    for (int j = 0; j < 2; ++j){
      int c = wave * 2 + j;
      int f = c & 3, ks = c >> 2;
      gload_lds16(kbase + (size_t)(t * 64 + f * 16 + lr) * 3072 + ks * 32 + lg * 8,
                  &K_lds[buf][c * 512 + lane * 8]);
      gload_lds16(vtb + (size_t)(f * 16 + lr) * NS + t * 64 + ks * 32 + lg * 8,
                  &V_lds[buf][c * 512 + lane * 8]);
    }
  };

  f32x4 oacc[4] = {};
  float mrow[4], lpart[4];
  #pragma unroll
  for (int r = 0; r < 4; ++r){ mrow[r] = -3.0e38f; lpart[r] = 0.f; }

  stage(0, 0);
  __syncthreads();
  int buf = 0;

  #pragma unroll 1
  for (int t = 0; t < nt; ++t){
    if (t + 1 < nt) stage(t + 1, buf ^ 1);

    // QK^T from fragment-ordered LDS
    f32x4 sacc[4] = {};
    #pragma unroll
    for (int f = 0; f < 4; ++f){
      s16x8 k0 = *(const s16x8*)&K_lds[buf][(0 * 4 + f) * 512 + lane * 8];
      s16x8 k1 = *(const s16x8*)&K_lds[buf][(1 * 4 + f) * 512 + lane * 8];
      sacc[f] = __builtin_amdgcn_mfma_f32_16x16x32_bf16(qf0, k0, sacc[f], 0, 0, 0);
      sacc[f] = __builtin_amdgcn_mfma_f32_16x16x32_bf16(qf1, k1, sacc[f], 0, 0, 0);
    }

    // scale + causal mask (only final tile straddles the diagonal)
    const bool diag = (t == nt - 1);
    #pragma unroll
    for (int f = 0; f < 4; ++f)
      #pragma unroll
      for (int r = 0; r < 4; ++r){
        float sv = sacc[f][r] * 0.125f;
        if (diag){
          int key = t * 64 + f * 16 + lr;
          int qq = q0 + lg * 4 + r;
          if (key > qq) sv = -1e30f;
        }
        sacc[f][r] = sv;
      }

    // row max (in-reg over f, then 16-lane shuffle reduce)
    float mx[4];
    #pragma unroll
    for (int r = 0; r < 4; ++r){
      float m = fmaxf(fmaxf(sacc[0][r], sacc[1][r]), fmaxf(sacc[2][r], sacc[3][r]));
      #pragma unroll
      for (int off = 1; off < 16; off <<= 1) m = fmaxf(m, __shfl_xor(m, off));
      mx[r] = m;
    }
    // T13 defer-max: rescale only when a row max grew past THR=8
    bool stable = (mx[0] <= mrow[0] + 8.f) && (mx[1] <= mrow[1] + 8.f) &&
                  (mx[2] <= mrow[2] + 8.f) && (mx[3] <= mrow[3] + 8.f);
    if (!__all(stable)){
      #pragma unroll
      for (int r = 0; r < 4; ++r){
        float mnew = fmaxf(mrow[r], mx[r]);
        float alpha = __expf(mrow[r] - mnew);
        lpart[r] *= alpha;
        #pragma unroll
        for (int f = 0; f < 4; ++f) oacc[f][r] *= alpha;
        mrow[r] = mnew;
      }
    }
    // P = exp(S - m); per-lane partial row sums (reduced once at the end)
    #pragma unroll
    for (int f = 0; f < 4; ++f)
      #pragma unroll
      for (int r = 0; r < 4; ++r){
        float pv = __expf(sacc[f][r] - mrow[r]);
        sacc[f][r] = pv;
        lpart[r] += pv;
      }

    // P -> per-wave LDS (wave-local ordering only)
    #pragma unroll
    for (int f = 0; f < 4; ++f)
      #pragma unroll
      for (int r = 0; r < 4; ++r)
        P_lds[wave][(lg * 4 + r) * 72 + f * 16 + lr] = f2bf(sacc[f][r]);

    // P @ V from fragment-ordered LDS
    #pragma unroll
    for (int ks = 0; ks < 2; ++ks){
      s16x8 pf = *(const s16x8*)&P_lds[wave][lr * 72 + ks * 32 + lg * 8];
      #pragma unroll
      for (int f = 0; f < 4; ++f){
        s16x8 vf = *(const s16x8*)&V_lds[buf][(ks * 4 + f) * 512 + lane * 8];
        oacc[f] = __builtin_amdgcn_mfma_f32_16x16x32_bf16(pf, vf, oacc[f], 0, 0, 0);
      }
    }
    __syncthreads();
    buf ^= 1;
  }

  // final row-sum reduce and normalize
  float lsum[4];
  #pragma unroll
  for (int r = 0; r < 4; ++r){
    float s = lpart[r];
    #pragma unroll
    for (int off = 1; off < 16; off <<= 1) s += __shfl_xor(s, off);
    lsum[r] = s;
  }
  #pragma unroll
  for (int f = 0; f < 4; ++f)
    #pragma unroll
    for (int r = 0; r < 4; ++r){
      float v = oacc[f][r] / lsum[r];
      out[(size_t)(b * NS + q0 + lg * 4 + r) * ND + h * 64 + f * 16 + lr] = f2bf(v);
    }
}

// ---------------- residual + LayerNorm ----------------
__global__ __launch_bounds__(256)
void ln_kernel(const bf16* __restrict__ a, const bf16* __restrict__ dn,
               const float* __restrict__ gamma, const float* __restrict__ beta,
               float* __restrict__ out)
{
  const int row = blockIdx.x;
  const int tid = threadIdx.x;
  const int lane = tid & 63, wave = tid >> 6;
  const size_t base = (size_t)row * ND;
  ushort4 ua = *(const ushort4*)((const unsigned short*)a + base + tid * 4);
  ushort4 ud = *(const ushort4*)((const unsigned short*)dn + base + tid * 4);
  float y[4];
  y[0] = bfu2f(ua.x) + bfu2f(ud.x);
  y[1] = bfu2f(ua.y) + bfu2f(ud.y);
  y[2] = bfu2f(ua.z) + bfu2f(ud.z);
  y[3] = bfu2f(ua.w) + bfu2f(ud.w);
  float s = y[0] + y[1] + y[2] + y[3];
  float ss = y[0]*y[0] + y[1]*y[1] + y[2]*y[2] + y[3]*y[3];
  #pragma unroll
  for (int off = 1; off < 64; off <<= 1){
    s  += __shfl_xor(s, off);
    ss += __shfl_xor(ss, off);
  }
  __shared__ float rs[4], rss[4];
  if (lane == 0){ rs[wave] = s; rss[wave] = ss; }
  __syncthreads();
  const float S  = rs[0] + rs[1] + rs[2] + rs[3];
  const float SS = rss[0] + rss[1] + rss[2] + rss[3];
  const float mu = S * (1.f / 1024.f);
  const float var = SS * (1.f / 1024.f) - mu * mu;
  const float inv = rsqrtf(var + 1e-6f);
  #pragma unroll
  for (int j = 0; j < 4; ++j){
    int c = tid * 4 + j;
    out[base + c] = (y[j] - mu) * inv * gamma[c] + beta[c];
  }
}

// ---------------- launcher ----------------
extern "C" void kernel_launch(void* const* d_in, const int* in_sizes, int n_in,
                              void* d_out, int out_size, void* d_ws, size_t ws_size,
                              hipStream_t stream)
{
  (void)in_sizes; (void)n_in; (void)out_size; (void)ws_size;
  const float* x  = (const float*)d_in[0];
  const float* Wq = (const float*)d_in[2];
  const float* bq = (const float*)d_in[3];
  const float* Wk = (const float*)d_in[4];
  const float* bk = (const float*)d_in[5];
  const float* Wv = (const float*)d_in[6];
  const float* bv = (const float*)d_in[7];
  const float* Wo = (const float*)d_in[8];
  const float* bo = (const float*)d_in[9];
  const float* W1 = (const float*)d_in[10];
  const float* b1 = (const float*)d_in[11];
  const float* W2 = (const float*)d_in[12];
  const float* b2 = (const float*)d_in[13];
  const float* gamma = (const float*)d_in[14];
  const float* beta  = (const float*)d_in[15];
  float* out = (float*)d_out;

  char* ws = (char*)d_ws;
  bf16* x_bf    = (bf16*)(ws + 0);          //  8,388,608
  bf16* wqkvT   = (bf16*)(ws + 8388608);    //  6,291,456  [3072][1024]
  bf16* woT     = (bf16*)(ws + 14680064);   //  2,097,152
  bf16* w1T     = (bf16*)(ws + 16777216);   //  8,388,608  [4096][1024]
  bf16* w2T     = (bf16*)(ws + 25165824);   //  8,388,608  [1024][4096]
  float* bqkv   = (float*)(ws + 33554432);  //     12,288
  bf16* qkv     = (bf16*)(ws + 33566720);   // 25,165,824  [4096][3072]
  bf16* vT      = (bf16*)(ws + 58732544);   //  8,388,608  [32][64][2048]
  bf16* attn    = (bf16*)(ws + 67121152);   //  8,388,608
  bf16* attnout = (bf16*)(ws + 75509760);   //  8,388,608
  bf16* down    = (bf16*)(ws + 83898368);   //  8,388,608
  bf16* hbuf    = (bf16*)(ws + 92286976);   // 33,554,432  [4096][4096]

  convert_kernel<<<4096, 256, 0, stream>>>(x, (unsigned short*)x_bf, 1048576);
  transpose_convert<<<dim3(32, 32), 256, 0, stream>>>(Wq, wqkvT,               1024, 1024);
  transpose_convert<<<dim3(32, 32), 256, 0, stream>>>(Wk, wqkvT + 1024 * 1024, 1024, 1024);
  transpose_convert<<<dim3(32, 32), 256, 0, stream>>>(Wv, wqkvT + 2048 * 1024, 1024, 1024);
  transpose_convert<<<dim3(32, 32), 256, 0, stream>>>(Wo, woT, 1024, 1024);
  transpose_convert<<<dim3(128, 32), 256, 0, stream>>>(W1, w1T, 1024, 4096);
  transpose_convert<<<dim3(32, 128), 256, 0, stream>>>(W2, w2T, 4096, 1024);
  pack_bias_kernel<<<12, 256, 0, stream>>>(bq, bk, bv, bqkv);

  gemm_bf16<1, 128><<<768, 256, 0, stream>>>(x_bf, wqkvT, bqkv, qkv, vT, 4096, 3072, 1024);
  attn_kernel<<<dim3(32, 32), 256, 0, stream>>>(qkv, vT, attn);
  gemm_bf16<0, 64><<<512, 256, 0, stream>>>(attn, woT, bo, attnout, nullptr, 4096, 1024, 1024);
  gemm_bf16<2, 128><<<1024, 256, 0, stream>>>(attnout, w1T, b1, hbuf, nullptr, 4096, 4096, 1024);
  gemm_bf16<0, 64><<<512, 256, 0, stream>>>(hbuf, w2T, b2, down, nullptr, 4096, 1024, 4096);
  ln_kernel<<<4096, 256, 0, stream>>>(attnout, down, gamma, beta, out);
}